// Round 2
// baseline (6258.818 us; speedup 1.0000x reference)
//
#include <hip/hip_runtime.h>
#include <hip/hip_bf16.h>

typedef unsigned int u32;
typedef unsigned short u16;

#define MTOT 31936      // B*N = 64*499
#define NN 499
#define BB 64

// ---------- helpers ----------
__device__ __forceinline__ float lo16(u32 u){ return __uint_as_float(u << 16); }
__device__ __forceinline__ float hi16(u32 u){ return __uint_as_float(u & 0xffff0000u); }
__device__ __forceinline__ float bf2f(u16 u){ return __uint_as_float(((u32)u) << 16); }
__device__ __forceinline__ u16 f2bf(float f){
  u32 x = __float_as_uint(f);
  u32 r = (x + 0x7fffu + ((x >> 16) & 1u)) >> 16;   // RNE
  return (u16)r;
}
__device__ __forceinline__ float sigf(float x){ return 1.f / (1.f + __expf(-x)); }
__device__ __forceinline__ float tanh_(float x){ return 2.f * sigf(2.f * x) - 1.f; }
__device__ __forceinline__ float wred(float v){
  #pragma unroll
  for (int off = 32; off; off >>= 1) v += __shfl_down(v, off, 64);
  return v;
}

typedef __attribute__((ext_vector_type(2))) __bf16 bf16x2;

// pack two f32 -> u32 of two bf16 (RNE)
#if __has_builtin(__builtin_amdgcn_cvt_pk_bf16_f32)
__device__ __forceinline__ u32 pk2bf(float a, float b){
  union { bf16x2 v; u32 u; } r;
  r.v = __builtin_amdgcn_cvt_pk_bf16_f32(a, b);
  return r.u;
}
#else
__device__ __forceinline__ u32 pk2bf(float a, float b){
  return (u32)f2bf(a) | ((u32)f2bf(b) << 16);
}
#endif

// ---------- MFMA plumbing (16x16x32 bf16) ----------
// A-frag: lane holds A[m=lane&15][k=(lane>>4)*8 + j], j=0..7  (8 bf16 = uint4)
// B-frag: lane holds B[k=(lane>>4)*8 + j][n=lane&15]
// C/D   : reg r at row=(lane>>4)*4+r, col=lane&15
typedef __attribute__((ext_vector_type(8))) short bfrag8;
typedef __attribute__((ext_vector_type(4))) float f4_t;
union FragU { uint4 u; bfrag8 s; };

__device__ __forceinline__ f4_t mfma16(FragU a, FragU b, f4_t c){
  return __builtin_amdgcn_mfma_f32_16x16x32_bf16(a.s, b.s, c, 0, 0, 0);
}

// GEMM core v2: 64M x 128N tile, 4 waves; ntBase selects this wave's 2 N-tiles.
// A (64Mx32K per kt) staged in LDS (double-buffered, one barrier/kt); B frags from global.
template <typename AL>
__device__ __forceinline__ void gemm_core2(int K32, const uint4* __restrict__ Bpack,
                                           int ntBase, f4_t (&acc)[4][2], AL aload){
  __shared__ __align__(16) uint4 As[2][256];
  const int tid = threadIdx.x;
  const int lane = tid & 63;
  const uint4* Bp0 = Bpack + ((size_t)ntBase * K32) * 64 + lane;
  const uint4* Bp1 = Bp0 + (size_t)K32 * 64;
  int buf = 0;
  for (int kt = 0; kt < K32; kt++){
    FragU b0, b1;
    b0.u = Bp0[kt * 64];
    b1.u = Bp1[kt * 64];
    As[buf][tid] = aload(kt);
    __syncthreads();
    FragU a0, a1, a2, a3;
    a0.u = As[buf][lane];
    a1.u = As[buf][64 + lane];
    a2.u = As[buf][128 + lane];
    a3.u = As[buf][192 + lane];
    acc[0][0] = mfma16(a0, b0, acc[0][0]); acc[0][1] = mfma16(a0, b1, acc[0][1]);
    acc[1][0] = mfma16(a1, b0, acc[1][0]); acc[1][1] = mfma16(a1, b1, acc[1][1]);
    acc[2][0] = mfma16(a2, b0, acc[2][0]); acc[2][1] = mfma16(a2, b1, acc[2][1]);
    acc[3][0] = mfma16(a3, b0, acc[3][0]); acc[3][1] = mfma16(a3, b1, acc[3][1]);
    buf ^= 1;
  }
}

// ---------- prep: pack weight matrix into B-fragment-layout bf16 chunks ----------
// chunk c: nt=c/(K32*64), kt=(c/64)%K32, l=c&63 -> holds B[k=kt*32+(l>>4)*8+j][n=nt*16+(l&15)]
// trans=0: B[k][n] = W[k*N+n] ; trans=1: B[k][n] = W[n*K+k]
__global__ __launch_bounds__(256) void k_packB(const float* __restrict__ W, u16* __restrict__ out,
                                               int K, int N, int trans){
  int c = blockIdx.x * 256 + threadIdx.x;
  int K32 = K >> 5;
  int total = (N >> 4) * K32 * 64;
  if (c >= total) return;
  int l = c & 63;
  int rem = c >> 6;
  int kt = rem % K32, nt = rem / K32;
  int n = nt * 16 + (l & 15);
  int kb = kt * 32 + (l >> 4) * 8;
  u32 ov[4];
  #pragma unroll
  for (int j2 = 0; j2 < 4; j2++){
    int k = kb + j2 * 2;
    float f0 = trans ? W[(size_t)n * K + k]     : W[(size_t)k * N + n];
    float f1 = trans ? W[(size_t)n * K + k + 1] : W[(size_t)(k + 1) * N + n];
    ov[j2] = pk2bf(f0, f1);
  }
  uint4 o; o.x = ov[0]; o.y = ov[1]; o.z = ov[2]; o.w = ov[3];
  *(uint4*)(out + (size_t)c * 8) = o;
}

// ---------- CSR build (chain graph, in-degree <= 3) ----------
__global__ void k_csr(const int* __restrict__ src, const int* __restrict__ dst, int E,
                      int* __restrict__ deg, int* __restrict__ insrc){
  int tid = threadIdx.x;
  for (int i = tid; i < NN; i += 256) deg[i] = 0;
  for (int i = tid; i < NN * 4; i += 256) insrc[i] = 0;
  __syncthreads();
  for (int e = tid; e < E; e += 256){
    int d = dst[e];
    int slot = atomicAdd(&deg[d], 1);
    if (slot < 4) insrc[d * 4 + slot] = src[e];
  }
}

// ---------- GEMM 1 (MFMA): x0 = concat(emb_p[p], emb_aff[aff]) @ W_affcat + b ; K=512, N=256, f32 out
__global__ __launch_bounds__(256) void k_affcat_m(
    const float* __restrict__ emb_p, const float* __restrict__ emb_aff,
    const int* __restrict__ p, const int* __restrict__ aff,
    const uint4* __restrict__ Bpack, const float* __restrict__ bias, float* __restrict__ C){
  const int tid = threadIdx.x;
  const int mBase = blockIdx.x * 64, nBase = blockIdx.y * 128;
  const int ls = tid & 63;
  const int gm = mBase + (tid >> 6) * 16 + (ls & 15);
  const int kqoff = (ls >> 4) * 8;
  const float* rp = emb_p + (size_t)p[gm] * 256 + kqoff;
  const float* ra = emb_aff + (size_t)aff[gm] * 256 + kqoff;
  f4_t acc[4][2] = {};
  gemm_core2(16, Bpack, blockIdx.y * 8 + ((tid >> 6) << 1), acc, [&](int kt) -> uint4 {
    int kb = kt * 32;
    const float* s = (kb < 256) ? (rp + kb) : (ra + kb - 256);
    float4 v0 = *(const float4*)s;
    float4 v1 = *(const float4*)(s + 4);
    uint4 o; o.x = pk2bf(v0.x, v0.y); o.y = pk2bf(v0.z, v0.w);
    o.z = pk2bf(v1.x, v1.y); o.w = pk2bf(v1.z, v1.w);
    return o;
  });
  const int wave = tid >> 6, lane = tid & 63;
  const int rb = (lane >> 4) << 2;
  const int cbase = nBase + wave * 32 + (lane & 15);
  float b0 = bias[cbase], b1 = bias[cbase + 16];
  #pragma unroll
  for (int i = 0; i < 4; i++)
    #pragma unroll
    for (int r = 0; r < 4; r++){
      int row = mBase + i * 16 + rb + r;
      C[(size_t)row * 256 + cbase]      = acc[i][0][r] + b0;
      C[(size_t)row * 256 + cbase + 16] = acc[i][1][r] + b1;
    }
}

// ---------- GEMM 2 (MFMA): h1 = x0 @ W_g1 ; K=256, N=1024, bf16 out
__global__ __launch_bounds__(256) void k_h1_m(const float* __restrict__ A,
                                              const uint4* __restrict__ Bpack,
                                              u16* __restrict__ Cb){
  const int tid = threadIdx.x;
  const int mBase = blockIdx.x * 64, nBase = blockIdx.y * 128;
  const int ls = tid & 63;
  const int gm = mBase + (tid >> 6) * 16 + (ls & 15);
  const float* ra = A + (size_t)gm * 256 + (ls >> 4) * 8;
  f4_t acc[4][2] = {};
  gemm_core2(8, Bpack, blockIdx.y * 8 + ((tid >> 6) << 1), acc, [&](int kt) -> uint4 {
    const float* s = ra + kt * 32;
    float4 v0 = *(const float4*)s;
    float4 v1 = *(const float4*)(s + 4);
    uint4 o; o.x = pk2bf(v0.x, v0.y); o.y = pk2bf(v0.z, v0.w);
    o.z = pk2bf(v1.x, v1.y); o.w = pk2bf(v1.z, v1.w);
    return o;
  });
  const int wave = tid >> 6, lane = tid & 63;
  const int rb = (lane >> 4) << 2;
  const int cbase = nBase + wave * 32 + (lane & 15);
  #pragma unroll
  for (int i = 0; i < 4; i++)
    #pragma unroll
    for (int r = 0; r < 4; r++){
      int row = mBase + i * 16 + rb + r;
      Cb[(size_t)row * 1024 + cbase]      = f2bf(acc[i][0][r]);
      Cb[(size_t)row * 1024 + cbase + 16] = f2bf(acc[i][1][r]);
    }
}

// ---------- GEMM 3 (MFMA): h2 = g1out @ W_g2 ; K=1024, N=256, f32 out ; A already bf16
__global__ __launch_bounds__(256) void k_h2_m(const u16* __restrict__ A,
                                              const uint4* __restrict__ Bpack,
                                              float* __restrict__ C){
  const int tid = threadIdx.x;
  const int mBase = blockIdx.x * 64, nBase = blockIdx.y * 128;
  const int ls = tid & 63;
  const int gm = mBase + (tid >> 6) * 16 + (ls & 15);
  const u16* ra = A + (size_t)gm * 1024 + (ls >> 4) * 8;
  f4_t acc[4][2] = {};
  gemm_core2(32, Bpack, blockIdx.y * 8 + ((tid >> 6) << 1), acc, [&](int kt) -> uint4 {
    return *(const uint4*)(ra + kt * 32);
  });
  const int wave = tid >> 6, lane = tid & 63;
  const int rb = (lane >> 4) << 2;
  const int cbase = nBase + wave * 32 + (lane & 15);
  #pragma unroll
  for (int i = 0; i < 4; i++)
    #pragma unroll
    for (int r = 0; r < 4; r++){
      int row = mBase + i * 16 + rb + r;
      C[(size_t)row * 256 + cbase]      = acc[i][0][r];
      C[(size_t)row * 256 + cbase + 16] = acc[i][1][r];
    }
}

// ---------- GEMM 4 (MFMA): gates = concat(p,q,r,x2) @ W_ih^T + bih + bhh ; K=1024, N=1024, bf16 out
// (round-0-proven structure; standard [row][1024] output layout)
__global__ __launch_bounds__(256) void k_gates_m(
    const float* __restrict__ emb_p, const float* __restrict__ emb_q, const float* __restrict__ emb_r,
    const int* __restrict__ p, const int* __restrict__ q, const int* __restrict__ r,
    const float* __restrict__ x2, const uint4* __restrict__ Bpack,
    const float* __restrict__ bih, const float* __restrict__ bhh, u16* __restrict__ Cb){
  const int tid = threadIdx.x;
  const int mBase = blockIdx.x * 64, nBase = blockIdx.y * 128;
  const int ls = tid & 63;
  const int gm = mBase + (tid >> 6) * 16 + (ls & 15);
  const int kqoff = (ls >> 4) * 8;
  const float* s0 = emb_p + (size_t)p[gm] * 256 + kqoff;
  const float* s1 = emb_q + (size_t)q[gm] * 256 + kqoff;
  const float* s2 = emb_r + (size_t)r[gm] * 256 + kqoff;
  const float* s3 = x2 + (size_t)gm * 256 + kqoff;
  f4_t acc[4][2] = {};
  gemm_core2(32, Bpack, blockIdx.y * 8 + ((tid >> 6) << 1), acc, [&](int kt) -> uint4 {
    int kb = kt * 32;
    int seg = kb >> 8, ko = kb & 255;
    const float* s = (seg == 0) ? s0 : ((seg == 1) ? s1 : ((seg == 2) ? s2 : s3));
    float4 v0 = *(const float4*)(s + ko);
    float4 v1 = *(const float4*)(s + ko + 4);
    uint4 o; o.x = pk2bf(v0.x, v0.y); o.y = pk2bf(v0.z, v0.w);
    o.z = pk2bf(v1.x, v1.y); o.w = pk2bf(v1.z, v1.w);
    return o;
  });
  const int wave = tid >> 6, lane = tid & 63;
  const int rb = (lane >> 4) << 2;
  const int cbase = nBase + wave * 32 + (lane & 15);
  float b0 = bih[cbase] + bhh[cbase];
  float b1 = bih[cbase + 16] + bhh[cbase + 16];
  #pragma unroll
  for (int i = 0; i < 4; i++)
    #pragma unroll
    for (int r2 = 0; r2 < 4; r2++){
      int row = mBase + i * 16 + rb + r2;
      Cb[(size_t)row * 1024 + cbase]      = f2bf(acc[i][0][r2] + b0);
      Cb[(size_t)row * 1024 + cbase + 16] = f2bf(acc[i][1][r2] + b1);
    }
}

// ---------- repack gates [row=b*NN+n][1024] -> LSTM stream layout ----------
// out u16 idx: ((((bg*NN+n)*8 + w)*64 + L)*32 + t*4 + rt)
//   value = gates[(bg*16 + ((L>>4)<<2) + rt)*NN + n][g*256 + w*32 + ut*16 + (L&15)]
//   with g = t&3, ut = t>>2. Block = (n, w); LDS-staged; coalesced 16B in/out.
__global__ __launch_bounds__(256) void k_repack(const u16* __restrict__ gates,
                                                u16* __restrict__ G0L){
  __shared__ __align__(16) u16 staged[64][128];
  const int tid = threadIdx.x;
  const int n = blockIdx.x, w = blockIdx.y;
  #pragma unroll
  for (int i = 0; i < 4; i++){
    const int c = tid + i * 256;           // 1024 chunks of 8 u16
    const int b = c >> 4, seg = c & 15;    // staged[b][seg*8 .. +8)
    const int t = seg >> 1, cc8 = (seg & 1) * 8;
    const int g = t & 3, ut = t >> 2;
    const u16* srcp = gates + (size_t)(b * NN + n) * 1024 + g * 256 + w * 32 + ut * 16 + cc8;
    *(uint4*)&staged[b][seg * 8] = *(const uint4*)srcp;
  }
  __syncthreads();
  const int Lt = tid >> 2, qq = tid & 3;
  const int mhi = (Lt >> 4) << 2;
  const int cc = Lt & 15;
  #pragma unroll
  for (int bg = 0; bg < 4; bg++){
    u32 vw[4];
    #pragma unroll
    for (int j = 0; j < 4; j++){
      const int t = 2 * qq + (j >> 1);
      const int r0 = (2 * j) & 3;          // 0,2,0,2
      const u16 lo = staged[bg * 16 + mhi + r0][t * 16 + cc];
      const u16 hi = staged[bg * 16 + mhi + r0 + 1][t * 16 + cc];
      vw[j] = (u32)lo | ((u32)hi << 16);
    }
    uint4 o; o.x = vw[0]; o.y = vw[1]; o.z = vw[2]; o.w = vw[3];
    *(uint4*)(G0L + ((((size_t)(bg * NN + n) * 8 + w) * 64 + Lt) * 32 + qq * 8)) = o;
  }
}

// ---------- es/ed: per (m,h) dots of h-row with a_src / a_dst ; one wave per w = m*H+h
__global__ __launch_bounds__(256) void k_esed(
    const u16* __restrict__ hb, const float* __restrict__ hf,
    const float* __restrict__ asrc, const float* __restrict__ adst,
    float* __restrict__ es, float* __restrict__ ed, int Hm1, int Fo){
  int w = blockIdx.x * 4 + (threadIdx.x >> 6);
  int lane = threadIdx.x & 63;
  int h = w & Hm1;
  size_t base = (size_t)w * Fo;
  float s = 0.f, d = 0.f;
  for (int f = lane; f < Fo; f += 64){
    float hv = hb ? bf2f(hb[base + f]) : hf[base + f];
    s += hv * asrc[h * Fo + f];
    d += hv * adst[h * Fo + f];
  }
  s = wred(s); d = wred(d);
  if (!lane){ es[w] = s; ed[w] = d; }
}

// ---------- GAT aggregation: segment softmax (deg<=3) + weighted sum + bias (+ELU)
__global__ __launch_bounds__(256) void k_gatagg(
    const u16* __restrict__ hb, const float* __restrict__ hf,
    const float* __restrict__ es, const float* __restrict__ ed,
    const int* __restrict__ deg, const int* __restrict__ insrc,
    const float* __restrict__ bias, u16* __restrict__ outb, float* __restrict__ outf,
    int H, int foShift, int HFo, int do_elu){
  int m = blockIdx.x;
  int b = m / NN;
  int n = m - b * NN;
  int dg = deg[n];
  int s0 = insrc[n * 4 + 0];
  int s1 = insrc[n * 4 + 1];
  int s2 = insrc[n * 4 + 2];
  int rowBase = b * NN;
  for (int c = threadIdx.x; c < HFo; c += 256){
    int h = c >> foShift;
    float edv = ed[(size_t)m * H + h];
    float sc0 = es[(size_t)(rowBase + s0) * H + h] + edv;
    sc0 = (sc0 >= 0.f) ? sc0 : 0.2f * sc0;
    float sc1 = 0.f, sc2 = 0.f, mx = sc0;
    if (dg > 1){ sc1 = es[(size_t)(rowBase + s1) * H + h] + edv; sc1 = (sc1 >= 0.f) ? sc1 : 0.2f * sc1; mx = fmaxf(mx, sc1); }
    if (dg > 2){ sc2 = es[(size_t)(rowBase + s2) * H + h] + edv; sc2 = (sc2 >= 0.f) ? sc2 : 0.2f * sc2; mx = fmaxf(mx, sc2); }
    float e0 = __expf(sc0 - mx), e1 = 0.f, e2 = 0.f;
    if (dg > 1) e1 = __expf(sc1 - mx);
    if (dg > 2) e2 = __expf(sc2 - mx);
    float inv = 1.f / (e0 + e1 + e2);
    size_t c0 = (size_t)(rowBase + s0) * HFo + c;
    float acc = e0 * (hb ? bf2f(hb[c0]) : hf[c0]);
    if (dg > 1){ size_t c1 = (size_t)(rowBase + s1) * HFo + c; acc += e1 * (hb ? bf2f(hb[c1]) : hf[c1]); }
    if (dg > 2){ size_t c2 = (size_t)(rowBase + s2) * HFo + c; acc += e2 * (hb ? bf2f(hb[c2]) : hf[c2]); }
    acc *= inv;
    float o = acc + bias[c];
    if (do_elu) o = (o > 0.f) ? o : (__expf(o) - 1.f);
    if (outb) outb[(size_t)m * HFo + c] = f2bf(o);
    else      outf[(size_t)m * HFo + c] = o;
  }
}

// ---------- LSTM recurrence v12 (MFMA, barrier-synced, L2-streamed weights) ----------
// 4 blocks (16 batches each) x 512 threads (8 waves). Per step:
//   G[16,1024] = H[16,256] @ W_hh^T  via 64x mfma_16x16x32_bf16 per wave
//   (wave w owns units [w*32,w*32+32) x all 4 gates -> gate math in-register).
// Weights: NOT resident; streamed from L2 every step through a 3-deep phase ring
//   wbuf[3][8] (96 VGPRs in flight, ~3-phase lead >= L2 latency). 512KB pack is
//   L2-resident per XCD; VMEM pipe is otherwise idle.
// h exchange: LDS double buffer hsh[2], XOR-swizzled (full-sum XOR: addr =
//   (m*512 + k*2bytes) ^ ((m&7)<<4)) for ~conflict-free ds_read_b128 A-frags.
// Sync: ONE barrier/step = lgkmcnt(0) + raw s_barrier + sched_barrier(0)
//   (raw barrier avoids __syncthreads' vmcnt(0) drain which would expose the
//   HBM latency of the just-issued gate prefetch each step).
// Gate prefetch: G0q for step n+1 issued at end of step n (~1 full step lead
//   > 900cy HBM latency); in-order vmcnt safe since issued after all ring loads.
__global__ __launch_bounds__(512)
void k_lstm(const u16* __restrict__ g0l,      // gates in k_repack layout
            const uint4* __restrict__ bph,    // packed W_hh^T B-frags (K=256,N=1024)
            float* __restrict__ h_all){
  __shared__ __align__(16) u16 hsh[2][4096];   // 16 KB double-buffered h
  const int bg = blockIdx.x, tid = threadIdx.x;
  const int w = tid >> 6, lane = tid & 63;
  const int am = lane & 15, oct = lane >> 4;
  const int hm = oct << 2, uc = am;
  const u32 abNos = (u32)(am * 512 + oct * 16);
  const u32 sw = (u32)((am & 7) << 4);
  ((uint4*)hsh[1])[tid] = make_uint4(0u, 0u, 0u, 0u);   // h(-1) = 0

  // per-t weight stream base pointers: frag (t, group g) at wp[t] + g*64
  const uint4* wp[8];
  #pragma unroll
  for (int t = 0; t < 8; t++){
    const int nt = (t & 3) * 16 + w * 2 + (t >> 2);
    wp[t] = bph + (size_t)(nt * 8) * 64 + lane;
  }
  // prologue: fill ring slots with groups 0,1,2
  uint4 wbuf[3][8];
  #pragma unroll
  for (int s = 0; s < 3; s++)
    #pragma unroll
    for (int t = 0; t < 8; t++) wbuf[s][t] = wp[t][s * 64];

  const uint4* g0p = (const uint4*)g0l + ((size_t)((size_t)bg * NN * 8 + w) * 64 + lane) * 4;
  uint4 G0q[4];
  G0q[0] = g0p[0]; G0q[1] = g0p[1]; G0q[2] = g0p[2]; G0q[3] = g0p[3];
  g0p += 2048;

  const size_t hofs0 = ((size_t)(bg * 16 + hm) * NN) * 256 + (size_t)w * 32 + uc;
  float cst[8] = {0.f, 0.f, 0.f, 0.f, 0.f, 0.f, 0.f, 0.f};
  __syncthreads();

  #pragma unroll 1
  for (int n = 0; n < NN; n++){
    const char* hrd = (const char*)hsh[(n + 1) & 1];   // h(n-1)
    char* hwr = (char*)hsh[n & 1];                     // h(n)
    // A-frags for all 8 k-chunks (swizzled ds_read_b128)
    FragU a[8];
    #pragma unroll
    for (int kc = 0; kc < 8; kc++)
      a[kc].u = *(const uint4*)(hrd + ((abNos + (u32)(kc * 64)) ^ sw));
    f4_t acc[8] = {};
    // 8 phases: consume ring slot, 8 MFMAs, reissue slot for its next use
    #pragma unroll
    for (int pp = 0; pp < 8; pp++){
      const int slot = pp % 3;
      const int gnext = (pp + 3 < 8) ? (pp + 3) : slot;   // next group this slot serves
      #pragma unroll
      for (int t = 0; t < 8; t++){
        FragU b; b.u = wbuf[slot][t];
        acc[t] = mfma16(a[pp], b, acc[t]);
      }
      #pragma unroll
      for (int t = 0; t < 8; t++) wbuf[slot][t] = wp[t][gnext * 64];
    }
    // gate math: lane owns (m = hm+rr, u = w*32+ut*16+uc); i/f/g/o in acc[ut*4+g]
    #pragma unroll
    for (int ut = 0; ut < 2; ut++){
      #pragma unroll
      for (int rr = 0; rr < 4; rr++){
        float gv[4];
        #pragma unroll
        for (int g = 0; g < 4; g++){
          const int t = ut * 4 + g;
          const uint4 qv = G0q[t >> 1];
          const int wi = ((t & 1) << 1) + (rr >> 1);
          const u32 uw = (wi == 0) ? qv.x : (wi == 1) ? qv.y : (wi == 2) ? qv.z : qv.w;
          gv[g] = acc[t][rr] + ((rr & 1) ? hi16(uw) : lo16(uw));
        }
        const int ci = ut * 4 + rr;
        const float cv = sigf(gv[1]) * cst[ci] + sigf(gv[0]) * tanh_(gv[2]);
        cst[ci] = cv;
        const float hv = sigf(gv[3]) * tanh_(cv);
        const int mm = hm + rr;
        const u32 wb = ((u32)(mm * 512 + (w * 32 + ut * 16 + uc) * 2)) ^ ((u32)(mm & 7) << 4);
        *(u16*)(hwr + wb) = f2bf(hv);
        h_all[hofs0 + (size_t)rr * (NN * 256) + (size_t)n * 256 + ut * 16] = hv;
      }
    }
    // issue next step's gate loads (consumed one full step later)
    if (n + 1 < NN){
      G0q[0] = g0p[0]; G0q[1] = g0p[1]; G0q[2] = g0p[2]; G0q[3] = g0p[3];
      g0p += 2048;
    }
    // publish h(n): drain LDS ops, barrier (no vmcnt drain), fence scheduling
    asm volatile("s_waitcnt lgkmcnt(0)" ::: "memory");
    __builtin_amdgcn_s_barrier();
    __builtin_amdgcn_sched_barrier(0);
  }
}

// ---------- final: y = sigmoid(concat(h, qn_emb, pn_emb) @ W_out + b_out) ; one wave per row
__global__ __launch_bounds__(256) void k_out(const float* __restrict__ h_all,
    const float* __restrict__ emb_q, const float* __restrict__ emb_p,
    const int* __restrict__ qn, const int* __restrict__ pn,
    const float* __restrict__ Wo, const float* __restrict__ bo, float* __restrict__ y){
  int m = blockIdx.x * 4 + (threadIdx.x >> 6);
  int lane = threadIdx.x & 63;
  const float* hr = h_all + (size_t)m * 256;
  const float* rq = emb_q + (size_t)qn[m] * 256;
  const float* rp = emb_p + (size_t)pn[m] * 256;
  float acc = 0.f;
  #pragma unroll
  for (int f = 0; f < 256; f += 64){
    int d = f + lane;
    acc += hr[d] * Wo[d];
    acc += rq[d] * Wo[256 + d];
    acc += rp[d] * Wo[512 + d];
  }
  acc = wred(acc);
  if (!lane) y[m] = sigf(acc + bo[0]);
}

// ---------- launch ----------
extern "C" void kernel_launch(void* const* d_in, const int* in_sizes, int n_in,
                              void* d_out, int out_size, void* d_ws, size_t ws_size,
                              hipStream_t stream){
  (void)n_in; (void)out_size; (void)ws_size;
  const int* p    = (const int*)d_in[1];
  const int* q    = (const int*)d_in[2];
  const int* r    = (const int*)d_in[3];
  const int* aff  = (const int*)d_in[4];
  const int* qn   = (const int*)d_in[5];
  const int* pn   = (const int*)d_in[6];
  const int* src  = (const int*)d_in[7];
  const int* dst  = (const int*)d_in[8];
  const float* emb_p  = (const float*)d_in[9];
  const float* emb_q  = (const float*)d_in[10];
  const float* emb_r  = (const float*)d_in[11];
  const float* emb_aff= (const float*)d_in[12];
  const float* W_aff  = (const float*)d_in[13];
  const float* b_aff  = (const float*)d_in[14];
  const float* W_g1   = (const float*)d_in[15];
  const float* a_s1   = (const float*)d_in[16];
  const float* a_d1   = (const float*)d_in[17];
  const float* b_g1   = (const float*)d_in[18];
  const float* W_g2   = (const float*)d_in[19];
  const float* a_s2   = (const float*)d_in[20];
  const float* a_d2   = (const float*)d_in[21];
  const float* b_g2   = (const float*)d_in[22];
  const float* W_ih   = (const float*)d_in[23];
  const float* W_hh   = (const float*)d_in[24];
  const float* b_ih   = (const float*)d_in[25];
  const float* b_hh   = (const float*)d_in[26];
  const float* W_out  = (const float*)d_in[27];
  const float* b_out  = (const float*)d_in[28];
  const int E = in_sizes[7];

  char* ws = (char*)d_ws;
  size_t off = 0;
  auto alloc = [&](size_t bytes){ size_t ret = off; off += (bytes + 255) & ~(size_t)255; return ret; };
  size_t o_bigA = alloc((size_t)MTOT * 1024 * 2);   // h1 bf16 -> gates bf16 (row layout)
  size_t o_bigB = alloc((size_t)MTOT * 1024 * 2);   // g1out bf16 -> x2 f32 -> G0L (lstm layout)
  size_t o_buf3 = alloc((size_t)MTOT * 256 * 4);    // x0 -> h2 -> h_all
  size_t o_es1 = alloc((size_t)MTOT * 8 * 4);
  size_t o_ed1 = alloc((size_t)MTOT * 8 * 4);
  size_t o_es2 = alloc((size_t)MTOT * 4);
  size_t o_ed2 = alloc((size_t)MTOT * 4);
  size_t o_whh = alloc((size_t)32768 * 16);      // W_hh^T B-frag pack (K=256,N=1024)
  size_t o_deg = alloc(512 * 4);
  size_t o_ins = alloc((size_t)NN * 4 * 4);
  size_t o_bpih  = alloc((size_t)131072 * 16);   // W_ih^T pack (K=1024,N=1024)
  size_t o_bpg1  = alloc((size_t)32768 * 16);    // W_g1 pack (K=256,N=1024)
  size_t o_bpg2  = alloc((size_t)32768 * 16);    // W_g2 pack (K=1024,N=256)
  size_t o_bpaff = alloc((size_t)16384 * 16);    // W_affcat pack (K=512,N=256)

  u16*   h1    = (u16*)(ws + o_bigA);
  u16*   gates = (u16*)(ws + o_bigA);
  u16*   g1out = (u16*)(ws + o_bigB);
  float* x2    = (float*)(ws + o_bigB);
  u16*   G0L   = (u16*)(ws + o_bigB);
  float* x0    = (float*)(ws + o_buf3);
  float* h2    = (float*)(ws + o_buf3);
  float* h_all = (float*)(ws + o_buf3);
  float* es1   = (float*)(ws + o_es1);
  float* ed1   = (float*)(ws + o_ed1);
  float* es2   = (float*)(ws + o_es2);
  float* ed2   = (float*)(ws + o_ed2);
  u16*   bphh  = (u16*)(ws + o_whh);
  int*   degp  = (int*)(ws + o_deg);
  int*   insp  = (int*)(ws + o_ins);
  u16*   bpih  = (u16*)(ws + o_bpih);
  u16*   bpg1  = (u16*)(ws + o_bpg1);
  u16*   bpg2  = (u16*)(ws + o_bpg2);
  u16*   bpaff = (u16*)(ws + o_bpaff);

  k_csr<<<1, 256, 0, stream>>>(src, dst, E, degp, insp);
  k_packB<<<128, 256, 0, stream>>>(W_hh, bphh, 256, 1024, 1);
  k_packB<<<512, 256, 0, stream>>>(W_ih, bpih, 1024, 1024, 1);
  k_packB<<<128, 256, 0, stream>>>(W_g1, bpg1, 256, 1024, 0);
  k_packB<<<128, 256, 0, stream>>>(W_g2, bpg2, 1024, 256, 0);
  k_packB<<<64, 256, 0, stream>>>(W_aff, bpaff, 512, 256, 0);

  k_affcat_m<<<dim3(NN, 2), 256, 0, stream>>>(emb_p, emb_aff, p, aff,
                                              (const uint4*)bpaff, b_aff, x0);
  k_h1_m<<<dim3(NN, 8), 256, 0, stream>>>(x0, (const uint4*)bpg1, h1);
  k_esed<<<(MTOT * 8) / 4, 256, 0, stream>>>(h1, nullptr, a_s1, a_d1, es1, ed1, 7, 128);
  k_gatagg<<<MTOT, 256, 0, stream>>>(h1, nullptr, es1, ed1, degp, insp, b_g1,
                                     g1out, nullptr, 8, 7, 1024, 1);
  k_h2_m<<<dim3(NN, 2), 256, 0, stream>>>(g1out, (const uint4*)bpg2, h2);
  k_esed<<<MTOT / 4, 256, 0, stream>>>(nullptr, h2, a_s2, a_d2, es2, ed2, 0, 256);
  k_gatagg<<<MTOT, 256, 0, stream>>>(nullptr, h2, es2, ed2, degp, insp, b_g2,
                                     nullptr, x2, 1, 8, 256, 0);
  k_gates_m<<<dim3(NN, 8), 256, 0, stream>>>(emb_p, emb_q, emb_r, p, q, r, x2,
                                             (const uint4*)bpih, b_ih, b_hh, gates);
  k_repack<<<dim3(NN, 8), 256, 0, stream>>>(gates, G0L);
  k_lstm<<<4, 512, 0, stream>>>(G0L, (const uint4*)bphh, h_all);
  k_out<<<MTOT / 4, 256, 0, stream>>>(h_all, emb_q, emb_p, qn, pn, W_out, b_out, (float*)d_out);
}